// Round 1
// baseline (1029.928 us; speedup 1.0000x reference)
//
#include <hip/hip_runtime.h>
#include <math.h>

#define Bn 2
#define Nn 50000
#define En 262144
#define Dn 256
#define Hn 1024
#define RTOT (Bn*Nn)

typedef short bf16x8 __attribute__((ext_vector_type(8)));
typedef float f32x4 __attribute__((ext_vector_type(4)));

__device__ __forceinline__ short f2b(float f) {
  unsigned u = __float_as_uint(f);
  u = u + 0x7fffu + ((u >> 16) & 1u);   // RNE to bf16
  return (short)(u >> 16);
}

// ---------- weight transpose + f32->bf16 ----------
__global__ void __launch_bounds__(256) wconv(
    const float* __restrict__ relw, const float* __restrict__ w1,
    const float* __restrict__ w2, short* __restrict__ relwT,
    short* __restrict__ w1T, short* __restrict__ w2T) {
  int tid = blockIdx.x * 256 + threadIdx.x;
  if (tid < Dn*Dn) { int c = tid >> 8, k = tid & 255; relwT[tid] = f2b(relw[k*Dn + c]); }
  int t1 = tid - Dn*Dn;
  if (t1 >= 0 && t1 < Dn*Hn) { int c = t1 >> 8, k = t1 & 255; w1T[t1] = f2b(w1[k*Hn + c]); }
  int t2 = tid - Dn*Dn - Dn*Hn;
  if (t2 >= 0 && t2 < Hn*Dn) { int c = t2 >> 10, k = t2 & 1023; w2T[t2] = f2b(w2[k*Dn + c]); }
}

// ---------- CSR build ----------
__global__ void __launch_bounds__(256) histk(const int* __restrict__ ei, int* __restrict__ cnt) {
  int tid = blockIdx.x * 256 + threadIdx.x;
  if (tid >= Bn*En) return;
  int b = tid / En;
  int tgt = ei[tid*2 + 1];
  atomicAdd(&cnt[b*Nn + tgt], 1);
}

__global__ void __launch_bounds__(1024) scank(const int* __restrict__ cnt, int* __restrict__ offs) {
  __shared__ int wsum[16];
  __shared__ int carry;
  int tid = threadIdx.x;
  int lane = tid & 63, wid = tid >> 6;
  if (tid == 0) carry = 0;
  __syncthreads();
  for (int base = 0; base < RTOT; base += 1024) {
    int i = base + tid;
    int v = (i < RTOT) ? cnt[i] : 0;
    int s = v;
#pragma unroll
    for (int d = 1; d < 64; d <<= 1) {
      int t = __shfl_up(s, d, 64);
      if (lane >= d) s += t;
    }
    if (lane == 63) wsum[wid] = s;
    __syncthreads();
    if (wid == 0) {
      int w = (lane < 16) ? wsum[lane] : 0;
#pragma unroll
      for (int d = 1; d < 16; d <<= 1) {
        int t = __shfl_up(w, d, 64);
        if (lane >= d) w += t;
      }
      if (lane < 16) wsum[lane] = w;
    }
    __syncthreads();
    int wprev = (wid == 0) ? 0 : wsum[wid - 1];
    int total = wsum[15];
    int excl = (s - v) + wprev + carry;
    if (i < RTOT) offs[i] = excl;
    __syncthreads();
    if (tid == 0) carry += total;
    __syncthreads();
  }
  if (tid == 0) offs[RTOT] = carry;
}

__global__ void __launch_bounds__(256) fillk(const int* __restrict__ ei, const int* __restrict__ offs,
                                             int* __restrict__ cursor, int* __restrict__ eids) {
  int tid = blockIdx.x * 256 + threadIdx.x;
  if (tid >= Bn*En) return;
  int b = tid / En, e = tid - b*En;
  int tgt = ei[tid*2 + 1];
  int node = b*Nn + tgt;
  int pos = atomicAdd(&cursor[node], 1);
  eids[offs[node] + pos] = e;
}

// ---------- aggregation: one wave per node ----------
__global__ void __launch_bounds__(256) aggk(
    const float* __restrict__ nodef, const float* __restrict__ erel,
    const float* __restrict__ emask, const int* __restrict__ ei,
    const int* __restrict__ offs, const int* __restrict__ eids,
    float* __restrict__ sumrel, float* __restrict__ cntf, float* __restrict__ outsrc) {
  int w = (blockIdx.x * 256 + threadIdx.x) >> 6;
  int lane = threadIdx.x & 63;
  if (w >= RTOT) return;
  int b = w / Nn;
  int s0 = offs[w], s1 = offs[w + 1];
  float r0=0,r1=0,r2=0,r3=0, a0=0,a1=0,a2=0,a3=0, cf=0;
  const size_t ebase = (size_t)b * En;
  const size_t nbase = (size_t)b * Nn;
  for (int j = s0; j < s1; j++) {
    int e = eids[j];
    int src = ei[(ebase + e)*2];
    float m = emask[ebase + e];
    float4 rv = *(const float4*)(erel + (ebase + e)*Dn + lane*4);
    float4 nv = *(const float4*)(nodef + (nbase + src)*Dn + lane*4);
    r0 += rv.x*m; r1 += rv.y*m; r2 += rv.z*m; r3 += rv.w*m;
    a0 += nv.x*m; a1 += nv.y*m; a2 += nv.z*m; a3 += nv.w*m;
    cf += m;
  }
  size_t ob = (size_t)w*Dn + lane*4;
  *(float4*)(sumrel + ob) = make_float4(r0,r1,r2,r3);
  *(float4*)(outsrc + ob) = make_float4(a0,a1,a2,a3);
  if (lane == 0) cntf[w] = cf;
}

// ---------- shared GEMM helpers ----------
__device__ __forceinline__ void stage64x256(const float* __restrict__ src, char* lds, int row0, int tid) {
#pragma unroll
  for (int i = 0; i < 16; i++) {
    int flat = tid + 256*i;
    int r = flat >> 6, c4 = flat & 63;
    int rg = row0 + r;
    float x0=0,x1=0,x2=0,x3=0;
    if (rg < RTOT) {
      float4 v = *(const float4*)(src + (size_t)rg*Dn + c4*4);
      x0=v.x; x1=v.y; x2=v.z; x3=v.w;
    }
    short4 s; s.x=f2b(x0); s.y=f2b(x1); s.z=f2b(x2); s.w=f2b(x3);
    int byte = r*512 + ((c4*8) ^ ((r & 7) << 4));   // XOR swizzle, G4
    *(short4*)(lds + byte) = s;
  }
}

__device__ __forceinline__ bf16x8 ldsA(const char* lds, int r, int kb) {
  int byte = r*512 + (((kb)*2) ^ ((r & 7) << 4));
  return *(const bf16x8*)(lds + byte);
}

// epilogue LayerNorm over 256-wide rows spread across 4 waves
__device__ __forceinline__ void ln_write(f32x4 (&acc)[4][4], float* red,
    const float* __restrict__ sc, const float* __restrict__ bi,
    float* __restrict__ out, int row0, int lane, int wv) {
  int l15 = lane & 15, l4 = lane >> 4;
  int cols[4]; float sc_c[4], bi_c[4];
#pragma unroll
  for (int n = 0; n < 4; n++) {
    cols[n] = wv*64 + n*16 + l15;
    sc_c[n] = sc[cols[n]]; bi_c[n] = bi[cols[n]];
  }
  float s1[4][4], s2[4][4];
#pragma unroll
  for (int m = 0; m < 4; m++)
#pragma unroll
    for (int g = 0; g < 4; g++) {
      float a = 0.f, b = 0.f;
#pragma unroll
      for (int n = 0; n < 4; n++) { float p = acc[m][n][g]; a += p; b += p*p; }
#pragma unroll
      for (int d = 1; d < 16; d <<= 1) { a += __shfl_xor(a, d, 16); b += __shfl_xor(b, d, 16); }
      s1[m][g] = a; s2[m][g] = b;
    }
  if (l15 == 0) {
#pragma unroll
    for (int m = 0; m < 4; m++)
#pragma unroll
      for (int g = 0; g < 4; g++) {
        int r = m*16 + l4*4 + g;
        red[(wv*64 + r)*2]     = s1[m][g];
        red[(wv*64 + r)*2 + 1] = s2[m][g];
      }
  }
  __syncthreads();
#pragma unroll
  for (int m = 0; m < 4; m++)
#pragma unroll
    for (int g = 0; g < 4; g++) {
      int r = m*16 + l4*4 + g; int rg = row0 + r;
      float t1 = 0.f, t2 = 0.f;
#pragma unroll
      for (int u = 0; u < 4; u++) { t1 += red[(u*64 + r)*2]; t2 += red[(u*64 + r)*2 + 1]; }
      float mean = t1 * (1.0f/Dn);
      float var  = t2 * (1.0f/Dn) - mean*mean;
      float rstd = rsqrtf(var + 1e-5f);
      if (rg < RTOT) {
#pragma unroll
        for (int n = 0; n < 4; n++)
          out[(size_t)rg*Dn + cols[n]] = (acc[m][n][g] - mean)*rstd*sc_c[n] + bi_c[n];
      }
    }
}

// ---------- K3: aggregated = (sum_src + sum_rel@W + cnt*b)/max(cnt,1); x = LN(node+agg) ----------
__global__ void __launch_bounds__(256) relln(
    const float* __restrict__ sumrel, const short* __restrict__ relwT,
    const float* __restrict__ relb, const float* __restrict__ nodef,
    const float* __restrict__ cntf, const float* __restrict__ ns,
    const float* __restrict__ nb, float* __restrict__ xout) {
  __shared__ __align__(16) char lds[32768 + 2048];
  float* red = (float*)(lds + 32768);
  int tid = threadIdx.x;
  int lane = tid & 63, wv = tid >> 6;
  int l15 = lane & 15, l4 = lane >> 4;
  int row0 = blockIdx.x * 64;
  stage64x256(sumrel, lds, row0, tid);
  __syncthreads();
  f32x4 acc[4][4] = {};
#pragma unroll
  for (int ks = 0; ks < 8; ks++) {
    bf16x8 af[4], bfr[4];
#pragma unroll
    for (int m = 0; m < 4; m++) af[m] = ldsA(lds, m*16 + l15, ks*32 + l4*8);
#pragma unroll
    for (int n = 0; n < 4; n++) {
      int col = wv*64 + n*16 + l15;
      bfr[n] = *(const bf16x8*)(relwT + col*Dn + ks*32 + l4*8);
    }
#pragma unroll
    for (int m = 0; m < 4; m++)
#pragma unroll
      for (int n = 0; n < 4; n++)
        acc[m][n] = __builtin_amdgcn_mfma_f32_16x16x32_bf16(af[m], bfr[n], acc[m][n], 0, 0, 0);
  }
  int cols[4]; float rb_c[4];
#pragma unroll
  for (int n = 0; n < 4; n++) { cols[n] = wv*64 + n*16 + l15; rb_c[n] = relb[cols[n]]; }
#pragma unroll
  for (int m = 0; m < 4; m++)
#pragma unroll
    for (int g = 0; g < 4; g++) {
      int r = m*16 + l4*4 + g; int rg = row0 + r;
      bool ok = rg < RTOT;
      float cf  = ok ? cntf[rg] : 0.f;
      float inv = 1.0f / fmaxf(cf, 1.0f);
#pragma unroll
      for (int n = 0; n < 4; n++) {
        float ssrc = ok ? xout[(size_t)rg*Dn + cols[n]] : 0.f;
        float nfv  = ok ? nodef[(size_t)rg*Dn + cols[n]] : 0.f;
        float aggv = (ssrc + acc[m][n][g] + cf*rb_c[n]) * inv;
        acc[m][n][g] = nfv + aggv;
      }
    }
  ln_write(acc, red, ns, nb, xout, row0, lane, wv);
}

// ---------- K4: fused FFN + residual + LN2, in-place on x ----------
__global__ void __launch_bounds__(256) ffnk(
    const short* __restrict__ w1T, const float* __restrict__ b1,
    const short* __restrict__ w2T, const float* __restrict__ b2,
    const float* __restrict__ fs, const float* __restrict__ fb,
    float* __restrict__ xio) {
  __shared__ __align__(16) char lds[65536 + 2048];
  char* Xs = lds; char* Hs = lds + 32768;
  float* red = (float*)(lds + 65536);
  int tid = threadIdx.x;
  int lane = tid & 63, wv = tid >> 6;
  int l15 = lane & 15, l4 = lane >> 4;
  int row0 = blockIdx.x * 64;
  stage64x256(xio, Xs, row0, tid);
  __syncthreads();
  f32x4 acc2[4][4] = {};
#pragma unroll 1
  for (int hc = 0; hc < 4; hc++) {
    f32x4 acc1[4][4] = {};
#pragma unroll
    for (int ks = 0; ks < 8; ks++) {
      bf16x8 af[4], bfr[4];
#pragma unroll
      for (int m = 0; m < 4; m++) af[m] = ldsA(Xs, m*16 + l15, ks*32 + l4*8);
#pragma unroll
      for (int n = 0; n < 4; n++) {
        int col = hc*256 + wv*64 + n*16 + l15;
        bfr[n] = *(const bf16x8*)(w1T + col*Dn + ks*32 + l4*8);
      }
#pragma unroll
      for (int m = 0; m < 4; m++)
#pragma unroll
        for (int n = 0; n < 4; n++)
          acc1[m][n] = __builtin_amdgcn_mfma_f32_16x16x32_bf16(af[m], bfr[n], acc1[m][n], 0, 0, 0);
    }
    // gelu (exact) -> Hs (bf16, swizzled)
#pragma unroll
    for (int n = 0; n < 4; n++) {
      int cc = wv*64 + n*16 + l15;
      float bb = b1[hc*256 + cc];
#pragma unroll
      for (int m = 0; m < 4; m++)
#pragma unroll
        for (int g = 0; g < 4; g++) {
          int r = m*16 + l4*4 + g;
          float v = acc1[m][n][g] + bb;
          float ge = 0.5f * v * (1.0f + erff(v * 0.70710678118654752f));
          *(short*)(Hs + r*512 + ((cc*2) ^ ((r & 7) << 4))) = f2b(ge);
        }
    }
    __syncthreads();
#pragma unroll
    for (int ks = 0; ks < 8; ks++) {
      bf16x8 af[4], bfr[4];
#pragma unroll
      for (int m = 0; m < 4; m++) af[m] = ldsA(Hs, m*16 + l15, ks*32 + l4*8);
#pragma unroll
      for (int n = 0; n < 4; n++) {
        int col = wv*64 + n*16 + l15;
        bfr[n] = *(const bf16x8*)(w2T + col*Hn + hc*256 + ks*32 + l4*8);
      }
#pragma unroll
      for (int m = 0; m < 4; m++)
#pragma unroll
        for (int n = 0; n < 4; n++)
          acc2[m][n] = __builtin_amdgcn_mfma_f32_16x16x32_bf16(af[m], bfr[n], acc2[m][n], 0, 0, 0);
    }
    __syncthreads();
  }
  // residual + b2 into acc2, then LN
  int cols[4]; float b2_c[4];
#pragma unroll
  for (int n = 0; n < 4; n++) { cols[n] = wv*64 + n*16 + l15; b2_c[n] = b2[cols[n]]; }
#pragma unroll
  for (int m = 0; m < 4; m++)
#pragma unroll
    for (int g = 0; g < 4; g++) {
      int r = m*16 + l4*4 + g; int rg = row0 + r;
      bool ok = rg < RTOT;
#pragma unroll
      for (int n = 0; n < 4; n++) {
        float xv = ok ? xio[(size_t)rg*Dn + cols[n]] : 0.f;
        acc2[m][n][g] = xv + acc2[m][n][g] + b2_c[n];
      }
    }
  ln_write(acc2, red, fs, fb, xio, row0, lane, wv);
}

// ---------- host ----------
extern "C" void kernel_launch(void* const* d_in, const int* in_sizes, int n_in,
                              void* d_out, int out_size, void* d_ws, size_t ws_size,
                              hipStream_t stream) {
  const float* nodef = (const float*)d_in[0];
  const float* erel  = (const float*)d_in[1];
  const float* emask = (const float*)d_in[2];
  const float* relw  = (const float*)d_in[3];
  const float* relb  = (const float*)d_in[4];
  const float* ns    = (const float*)d_in[5];
  const float* nb    = (const float*)d_in[6];
  const float* w1    = (const float*)d_in[7];
  const float* b1    = (const float*)d_in[8];
  const float* w2    = (const float*)d_in[9];
  const float* b2    = (const float*)d_in[10];
  const float* fs    = (const float*)d_in[11];
  const float* fb    = (const float*)d_in[12];
  const int*   ei    = (const int*)d_in[13];
  float* out = (float*)d_out;
  char* ws = (char*)d_ws;

  constexpr size_t SZ_SUMREL = (size_t)RTOT * Dn * 4;          // 102,400,000
  constexpr size_t O_CNT  = SZ_SUMREL;
  constexpr size_t O_CUR  = O_CNT + (size_t)RTOT*4;
  constexpr size_t O_OFF  = O_CUR + (size_t)RTOT*4;
  constexpr size_t O_EID  = O_OFF + ((size_t)(RTOT+1)*4 + 124); // pad to 16B
  constexpr size_t O_CNTF = O_EID + (size_t)Bn*En*4;
  constexpr size_t O_RWT  = O_CNTF + (size_t)RTOT*4;
  constexpr size_t O_W1T  = O_RWT + (size_t)Dn*Dn*2;
  constexpr size_t O_W2T  = O_W1T + (size_t)Dn*Hn*2;
  constexpr size_t WS_NEED = O_W2T + (size_t)Hn*Dn*2;          // ~107.3 MB
  if (ws_size < WS_NEED) return;

  float* sumrel = (float*)(ws);
  int*   cnt    = (int*)(ws + O_CNT);
  int*   cursor = (int*)(ws + O_CUR);
  int*   offs   = (int*)(ws + O_OFF);
  int*   eids   = (int*)(ws + O_EID);
  float* cntf   = (float*)(ws + O_CNTF);
  short* relwT  = (short*)(ws + O_RWT);
  short* w1T    = (short*)(ws + O_W1T);
  short* w2T    = (short*)(ws + O_W2T);

  // zero cnt + cursor (contiguous)
  hipMemsetAsync(ws + O_CNT, 0, (size_t)RTOT*8, stream);

  wconv<<<(Dn*Dn + Dn*Hn + Hn*Dn) / 256, 256, 0, stream>>>(relw, w1, w2, relwT, w1T, w2T);
  histk<<<(Bn*En) / 256, 256, 0, stream>>>(ei, cnt);
  scank<<<1, 1024, 0, stream>>>(cnt, offs);
  fillk<<<(Bn*En) / 256, 256, 0, stream>>>(ei, offs, cursor, eids);
  aggk<<<(RTOT + 3) / 4, 256, 0, stream>>>(nodef, erel, emask, ei, offs, eids, sumrel, cntf, out);
  relln<<<(RTOT + 63) / 64, 256, 0, stream>>>(sumrel, relwT, relb, nodef, cntf, ns, nb, out);
  ffnk<<<(RTOT + 63) / 64, 256, 0, stream>>>(w1T, b1, w2T, b2, fs, fb, out);
}

// Round 2
// 920.846 us; speedup vs baseline: 1.1185x; 1.1185x over previous
//
#include <hip/hip_runtime.h>
#include <math.h>

#define Bn 2
#define Nn 50000
#define En 262144
#define Dn 256
#define Hn 1024
#define RTOT (Bn*Nn)

typedef short bf16x8 __attribute__((ext_vector_type(8)));
typedef float f32x4 __attribute__((ext_vector_type(4)));

static_assert(RTOT % 32 == 0, "tile exact");

__device__ __forceinline__ short f2b(float f) {
  unsigned u = __float_as_uint(f);
  u = u + 0x7fffu + ((u >> 16) & 1u);   // RNE to bf16
  return (short)(u >> 16);
}

// ---------- weight transpose + f32->bf16 ----------
__global__ void __launch_bounds__(256) wconv(
    const float* __restrict__ relw, const float* __restrict__ w1,
    const float* __restrict__ w2, short* __restrict__ relwT,
    short* __restrict__ w1T, short* __restrict__ w2T) {
  int tid = blockIdx.x * 256 + threadIdx.x;
  if (tid < Dn*Dn) { int c = tid >> 8, k = tid & 255; relwT[tid] = f2b(relw[k*Dn + c]); }
  int t1 = tid - Dn*Dn;
  if (t1 >= 0 && t1 < Dn*Hn) { int c = t1 >> 8, k = t1 & 255; w1T[t1] = f2b(w1[k*Hn + c]); }
  int t2 = tid - Dn*Dn - Dn*Hn;
  if (t2 >= 0 && t2 < Hn*Dn) { int c = t2 >> 10, k = t2 & 1023; w2T[t2] = f2b(w2[k*Dn + c]); }
}

// ---------- CSR build ----------
__global__ void __launch_bounds__(256) histk(const int* __restrict__ ei, int* __restrict__ cnt) {
  int tid = blockIdx.x * 256 + threadIdx.x;
  if (tid >= Bn*En) return;
  int b = tid / En;
  int tgt = ei[tid*2 + 1];
  atomicAdd(&cnt[b*Nn + tgt], 1);
}

__global__ void __launch_bounds__(1024) scank(const int* __restrict__ cnt, int* __restrict__ offs) {
  __shared__ int wsum[16];
  __shared__ int carry;
  int tid = threadIdx.x;
  int lane = tid & 63, wid = tid >> 6;
  if (tid == 0) carry = 0;
  __syncthreads();
  for (int base = 0; base < RTOT; base += 1024) {
    int i = base + tid;
    int v = (i < RTOT) ? cnt[i] : 0;
    int s = v;
#pragma unroll
    for (int d = 1; d < 64; d <<= 1) {
      int t = __shfl_up(s, d, 64);
      if (lane >= d) s += t;
    }
    if (lane == 63) wsum[wid] = s;
    __syncthreads();
    if (wid == 0) {
      int w = (lane < 16) ? wsum[lane] : 0;
#pragma unroll
      for (int d = 1; d < 16; d <<= 1) {
        int t = __shfl_up(w, d, 64);
        if (lane >= d) w += t;
      }
      if (lane < 16) wsum[lane] = w;
    }
    __syncthreads();
    int wprev = (wid == 0) ? 0 : wsum[wid - 1];
    int total = wsum[15];
    int excl = (s - v) + wprev + carry;
    if (i < RTOT) offs[i] = excl;
    __syncthreads();
    if (tid == 0) carry += total;
    __syncthreads();
  }
  if (tid == 0) offs[RTOT] = carry;
}

__global__ void __launch_bounds__(256) fillk(const int* __restrict__ ei, const int* __restrict__ offs,
                                             int* __restrict__ cursor, int* __restrict__ eids) {
  int tid = blockIdx.x * 256 + threadIdx.x;
  if (tid >= Bn*En) return;
  int b = tid / En, e = tid - b*En;
  int tgt = ei[tid*2 + 1];
  int node = b*Nn + tgt;
  int pos = atomicAdd(&cursor[node], 1);
  eids[offs[node] + pos] = e;
}

// ---------- aggregation: one wave per node, metadata lane-parallel, dbuf prefetch ----------
__global__ void __launch_bounds__(256) aggk(
    const float* __restrict__ nodef, const float* __restrict__ erel,
    const float* __restrict__ emask, const int* __restrict__ ei,
    const int* __restrict__ offs, const int* __restrict__ eids,
    float* __restrict__ sumrel, float* __restrict__ cntf, float* __restrict__ outsrc) {
  int w = (blockIdx.x * 256 + threadIdx.x) >> 6;
  int lane = threadIdx.x & 63;
  if (w >= RTOT) return;
  int b = w / Nn;
  const size_t ebase = (size_t)b * En;
  const size_t nbase = (size_t)b * Nn;
  int s0 = offs[w], s1 = offs[w + 1];
  float r0=0,r1=0,r2=0,r3=0, a0=0,a1=0,a2=0,a3=0, cf=0;
  for (int base = s0; base < s1; base += 64) {
    int k = s1 - base; if (k > 64) k = 64;
    int e = 0, sr = 0; float m = 0.f;
    if (lane < k) {                       // lane-parallel metadata fetch
      e  = eids[base + lane];
      sr = ei[(ebase + e)*2];
      m  = emask[ebase + e];
    }
    int e0 = __shfl(e, 0), sr0 = __shfl(sr, 0);
    float m0 = __shfl(m, 0);
    float4 rvA = *(const float4*)(erel  + (ebase + e0)*Dn + lane*4);
    float4 nvA = *(const float4*)(nodef + (nbase + sr0)*Dn + lane*4);
    for (int j = 0; j < k; j++) {
      float4 rvB = make_float4(0,0,0,0), nvB = make_float4(0,0,0,0);
      float m1 = 0.f;
      if (j + 1 < k) {                    // prefetch next edge while consuming current
        int e1 = __shfl(e, j+1), sr1 = __shfl(sr, j+1);
        m1 = __shfl(m, j+1);
        rvB = *(const float4*)(erel  + (ebase + e1)*Dn + lane*4);
        nvB = *(const float4*)(nodef + (nbase + sr1)*Dn + lane*4);
      }
      r0 += rvA.x*m0; r1 += rvA.y*m0; r2 += rvA.z*m0; r3 += rvA.w*m0;
      a0 += nvA.x*m0; a1 += nvA.y*m0; a2 += nvA.z*m0; a3 += nvA.w*m0;
      cf += m0;
      rvA = rvB; nvA = nvB; m0 = m1;
    }
  }
  size_t ob = (size_t)w*Dn + lane*4;
  *(float4*)(sumrel + ob) = make_float4(r0,r1,r2,r3);
  *(float4*)(outsrc + ob) = make_float4(a0,a1,a2,a3);
  if (lane == 0) cntf[w] = cf;
}

// ---------- shared GEMM helpers (MR = number of 16-row groups per block) ----------
template<int MR>
__device__ __forceinline__ void stageX(const float* __restrict__ src, char* lds, int row0, int tid) {
#pragma unroll
  for (int i = 0; i < MR*4; i++) {
    int flat = tid + 256*i;
    int r = flat >> 6, c4 = flat & 63;
    float4 v = *(const float4*)(src + (size_t)(row0 + r)*Dn + c4*4);
    short4 s; s.x=f2b(v.x); s.y=f2b(v.y); s.z=f2b(v.z); s.w=f2b(v.w);
    int byte = r*512 + ((c4*8) ^ ((r & 7) << 4));   // XOR swizzle, G4
    *(short4*)(lds + byte) = s;
  }
}

__device__ __forceinline__ bf16x8 ldsA(const char* lds, int r, int kb) {
  int byte = r*512 + (((kb)*2) ^ ((r & 7) << 4));
  return *(const bf16x8*)(lds + byte);
}

// epilogue LayerNorm over 256-wide rows spread across 4 waves
template<int MR>
__device__ __forceinline__ void ln_write(f32x4 (&acc)[MR][4], float* red,
    const float* __restrict__ sc, const float* __restrict__ bi,
    float* __restrict__ out, int row0, int lane, int wv) {
  constexpr int R = MR*16;
  int l15 = lane & 15, l4 = lane >> 4;
  int cols[4]; float sc_c[4], bi_c[4];
#pragma unroll
  for (int n = 0; n < 4; n++) {
    cols[n] = wv*64 + n*16 + l15;
    sc_c[n] = sc[cols[n]]; bi_c[n] = bi[cols[n]];
  }
  float s1[MR][4], s2[MR][4];
#pragma unroll
  for (int m = 0; m < MR; m++)
#pragma unroll
    for (int g = 0; g < 4; g++) {
      float a = 0.f, b = 0.f;
#pragma unroll
      for (int n = 0; n < 4; n++) { float p = acc[m][n][g]; a += p; b += p*p; }
#pragma unroll
      for (int d = 1; d < 16; d <<= 1) { a += __shfl_xor(a, d, 16); b += __shfl_xor(b, d, 16); }
      s1[m][g] = a; s2[m][g] = b;
    }
  if (l15 == 0) {
#pragma unroll
    for (int m = 0; m < MR; m++)
#pragma unroll
      for (int g = 0; g < 4; g++) {
        int r = m*16 + l4*4 + g;
        red[(wv*R + r)*2]     = s1[m][g];
        red[(wv*R + r)*2 + 1] = s2[m][g];
      }
  }
  __syncthreads();
#pragma unroll
  for (int m = 0; m < MR; m++)
#pragma unroll
    for (int g = 0; g < 4; g++) {
      int r = m*16 + l4*4 + g; int rg = row0 + r;
      float t1 = 0.f, t2 = 0.f;
#pragma unroll
      for (int u = 0; u < 4; u++) { t1 += red[(u*R + r)*2]; t2 += red[(u*R + r)*2 + 1]; }
      float mean = t1 * (1.0f/Dn);
      float var  = t2 * (1.0f/Dn) - mean*mean;
      float rstd = rsqrtf(var + 1e-5f);
#pragma unroll
      for (int n = 0; n < 4; n++)
        out[(size_t)rg*Dn + cols[n]] = (acc[m][n][g] - mean)*rstd*sc_c[n] + bi_c[n];
    }
}

// ---------- K3: aggregated = (sum_src + sum_rel@W + cnt*b)/max(cnt,1); x = LN(node+agg) ----------
__global__ void __launch_bounds__(256, 4) relln(
    const float* __restrict__ sumrel, const short* __restrict__ relwT,
    const float* __restrict__ relb, const float* __restrict__ nodef,
    const float* __restrict__ cntf, const float* __restrict__ ns,
    const float* __restrict__ nb, float* __restrict__ xout) {
  constexpr int MR = 2;
  __shared__ __align__(16) char lds[16384 + 1024];
  float* red = (float*)(lds + 16384);
  int tid = threadIdx.x;
  int lane = tid & 63, wv = tid >> 6;
  int l15 = lane & 15, l4 = lane >> 4;
  int row0 = blockIdx.x * (MR*16);
  stageX<MR>(sumrel, lds, row0, tid);
  __syncthreads();
  f32x4 acc[MR][4] = {};
#pragma unroll
  for (int ks = 0; ks < 8; ks++) {
    bf16x8 af[MR], bfr[4];
#pragma unroll
    for (int m = 0; m < MR; m++) af[m] = ldsA(lds, m*16 + l15, ks*32 + l4*8);
#pragma unroll
    for (int n = 0; n < 4; n++) {
      int col = wv*64 + n*16 + l15;
      bfr[n] = *(const bf16x8*)(relwT + col*Dn + ks*32 + l4*8);
    }
#pragma unroll
    for (int m = 0; m < MR; m++)
#pragma unroll
      for (int n = 0; n < 4; n++)
        acc[m][n] = __builtin_amdgcn_mfma_f32_16x16x32_bf16(af[m], bfr[n], acc[m][n], 0, 0, 0);
  }
  int cols[4]; float rb_c[4];
#pragma unroll
  for (int n = 0; n < 4; n++) { cols[n] = wv*64 + n*16 + l15; rb_c[n] = relb[cols[n]]; }
#pragma unroll
  for (int m = 0; m < MR; m++)
#pragma unroll
    for (int g = 0; g < 4; g++) {
      int r = m*16 + l4*4 + g; int rg = row0 + r;
      float cf  = cntf[rg];
      float inv = 1.0f / fmaxf(cf, 1.0f);
#pragma unroll
      for (int n = 0; n < 4; n++) {
        float ssrc = xout[(size_t)rg*Dn + cols[n]];
        float nfv  = nodef[(size_t)rg*Dn + cols[n]];
        float aggv = (ssrc + acc[m][n][g] + cf*rb_c[n]) * inv;
        acc[m][n][g] = nfv + aggv;
      }
    }
  ln_write<MR>(acc, red, ns, nb, xout, row0, lane, wv);
}

// ---------- K4: fused FFN + residual + LN2, in-place on x ----------
__global__ void __launch_bounds__(256, 4) ffnk(
    const short* __restrict__ w1T, const float* __restrict__ b1,
    const short* __restrict__ w2T, const float* __restrict__ b2,
    const float* __restrict__ fs, const float* __restrict__ fb,
    float* __restrict__ xio) {
  constexpr int MR = 2;
  __shared__ __align__(16) char lds[32768 + 1024];
  char* Xs = lds; char* Hs = lds + 16384;
  float* red = (float*)(lds + 32768);
  int tid = threadIdx.x;
  int lane = tid & 63, wv = tid >> 6;
  int l15 = lane & 15, l4 = lane >> 4;
  int row0 = blockIdx.x * (MR*16);
  stageX<MR>(xio, Xs, row0, tid);
  __syncthreads();
  f32x4 acc2[MR][4] = {};
#pragma unroll 1
  for (int hc = 0; hc < 4; hc++) {
    f32x4 acc1[MR][4] = {};
#pragma unroll
    for (int ks = 0; ks < 8; ks++) {
      bf16x8 af[MR], bfr[4];
#pragma unroll
      for (int m = 0; m < MR; m++) af[m] = ldsA(Xs, m*16 + l15, ks*32 + l4*8);
#pragma unroll
      for (int n = 0; n < 4; n++) {
        int col = hc*256 + wv*64 + n*16 + l15;
        bfr[n] = *(const bf16x8*)(w1T + col*Dn + ks*32 + l4*8);
      }
#pragma unroll
      for (int m = 0; m < MR; m++)
#pragma unroll
        for (int n = 0; n < 4; n++)
          acc1[m][n] = __builtin_amdgcn_mfma_f32_16x16x32_bf16(af[m], bfr[n], acc1[m][n], 0, 0, 0);
    }
    // gelu (exact) -> Hs (bf16, swizzled)
#pragma unroll
    for (int n = 0; n < 4; n++) {
      int cc = wv*64 + n*16 + l15;
      float bb = b1[hc*256 + cc];
#pragma unroll
      for (int m = 0; m < MR; m++)
#pragma unroll
        for (int g = 0; g < 4; g++) {
          int r = m*16 + l4*4 + g;
          float v = acc1[m][n][g] + bb;
          float ge = 0.5f * v * (1.0f + erff(v * 0.70710678118654752f));
          *(short*)(Hs + r*512 + ((cc*2) ^ ((r & 7) << 4))) = f2b(ge);
        }
    }
    __syncthreads();
#pragma unroll
    for (int ks = 0; ks < 8; ks++) {
      bf16x8 af[MR], bfr[4];
#pragma unroll
      for (int m = 0; m < MR; m++) af[m] = ldsA(Hs, m*16 + l15, ks*32 + l4*8);
#pragma unroll
      for (int n = 0; n < 4; n++) {
        int col = wv*64 + n*16 + l15;
        bfr[n] = *(const bf16x8*)(w2T + col*Hn + hc*256 + ks*32 + l4*8);
      }
#pragma unroll
      for (int m = 0; m < MR; m++)
#pragma unroll
        for (int n = 0; n < 4; n++)
          acc2[m][n] = __builtin_amdgcn_mfma_f32_16x16x32_bf16(af[m], bfr[n], acc2[m][n], 0, 0, 0);
    }
    __syncthreads();
  }
  // residual + b2 into acc2, then LN
  int cols[4]; float b2_c[4];
#pragma unroll
  for (int n = 0; n < 4; n++) { cols[n] = wv*64 + n*16 + l15; b2_c[n] = b2[cols[n]]; }
#pragma unroll
  for (int m = 0; m < MR; m++)
#pragma unroll
    for (int g = 0; g < 4; g++) {
      int r = m*16 + l4*4 + g; int rg = row0 + r;
#pragma unroll
      for (int n = 0; n < 4; n++) {
        float xv = xio[(size_t)rg*Dn + cols[n]];
        acc2[m][n][g] = xv + acc2[m][n][g] + b2_c[n];
      }
    }
  ln_write<MR>(acc2, red, fs, fb, xio, row0, lane, wv);
}

// ---------- host ----------
extern "C" void kernel_launch(void* const* d_in, const int* in_sizes, int n_in,
                              void* d_out, int out_size, void* d_ws, size_t ws_size,
                              hipStream_t stream) {
  const float* nodef = (const float*)d_in[0];
  const float* erel  = (const float*)d_in[1];
  const float* emask = (const float*)d_in[2];
  const float* relw  = (const float*)d_in[3];
  const float* relb  = (const float*)d_in[4];
  const float* ns    = (const float*)d_in[5];
  const float* nb    = (const float*)d_in[6];
  const float* w1    = (const float*)d_in[7];
  const float* b1    = (const float*)d_in[8];
  const float* w2    = (const float*)d_in[9];
  const float* b2    = (const float*)d_in[10];
  const float* fs    = (const float*)d_in[11];
  const float* fb    = (const float*)d_in[12];
  const int*   ei    = (const int*)d_in[13];
  float* out = (float*)d_out;
  char* ws = (char*)d_ws;

  constexpr size_t SZ_SUMREL = (size_t)RTOT * Dn * 4;
  constexpr size_t O_CNT  = SZ_SUMREL;
  constexpr size_t O_CUR  = O_CNT + (size_t)RTOT*4;
  constexpr size_t O_OFF  = O_CUR + (size_t)RTOT*4;
  constexpr size_t O_EID  = O_OFF + ((size_t)(RTOT+1)*4 + 124);
  constexpr size_t O_CNTF = O_EID + (size_t)Bn*En*4;
  constexpr size_t O_RWT  = O_CNTF + (size_t)RTOT*4;
  constexpr size_t O_W1T  = O_RWT + (size_t)Dn*Dn*2;
  constexpr size_t O_W2T  = O_W1T + (size_t)Dn*Hn*2;
  constexpr size_t WS_NEED = O_W2T + (size_t)Hn*Dn*2;
  if (ws_size < WS_NEED) return;

  float* sumrel = (float*)(ws);
  int*   cnt    = (int*)(ws + O_CNT);
  int*   cursor = (int*)(ws + O_CUR);
  int*   offs   = (int*)(ws + O_OFF);
  int*   eids   = (int*)(ws + O_EID);
  float* cntf   = (float*)(ws + O_CNTF);
  short* relwT  = (short*)(ws + O_RWT);
  short* w1T    = (short*)(ws + O_W1T);
  short* w2T    = (short*)(ws + O_W2T);

  hipMemsetAsync(ws + O_CNT, 0, (size_t)RTOT*8, stream);

  wconv<<<(Dn*Dn + Dn*Hn + Hn*Dn) / 256, 256, 0, stream>>>(relw, w1, w2, relwT, w1T, w2T);
  histk<<<(Bn*En) / 256, 256, 0, stream>>>(ei, cnt);
  scank<<<1, 1024, 0, stream>>>(cnt, offs);
  fillk<<<(Bn*En) / 256, 256, 0, stream>>>(ei, offs, cursor, eids);
  aggk<<<(RTOT + 3) / 4, 256, 0, stream>>>(nodef, erel, emask, ei, offs, eids, sumrel, cntf, out);
  relln<<<RTOT / 32, 256, 0, stream>>>(sumrel, relwT, relb, nodef, cntf, ns, nb, out);
  ffnk<<<RTOT / 32, 256, 0, stream>>>(w1T, b1, w2T, b2, fs, fb, out);
}

// Round 3
// 791.042 us; speedup vs baseline: 1.3020x; 1.1641x over previous
//
#include <hip/hip_runtime.h>
#include <math.h>

#define Bn 2
#define Nn 50000
#define En 262144
#define Dn 256
#define Hn 1024
#define RTOT (Bn*Nn)

typedef short bf16x8 __attribute__((ext_vector_type(8)));
typedef float f32x4 __attribute__((ext_vector_type(4)));

__device__ __forceinline__ short f2b(float f) {
  unsigned u = __float_as_uint(f);
  u = u + 0x7fffu + ((u >> 16) & 1u);   // RNE to bf16
  return (short)(u >> 16);
}

// cheap exact-enough erf (A&S 7.1.26, |err|<=1.5e-7) -> gelu
__device__ __forceinline__ float gelu_f(float v) {
  float x = fabsf(v) * 0.70710678118654752f;
  float t = __builtin_amdgcn_rcpf(1.0f + 0.3275911f * x);
  float p = ((((1.061405429f*t - 1.453152027f)*t + 1.421413741f)*t
              - 0.284496736f)*t + 0.254829592f)*t;
  float e = __expf(-x*x);
  float er = 1.0f - p*e;                 // erf(|v|/sqrt2)
  er = copysignf(er, v);
  return 0.5f * v * (1.0f + er);
}

__device__ __forceinline__ void gl16(const void* g, void* l) {
  __builtin_amdgcn_global_load_lds(
      (const __attribute__((address_space(1))) unsigned int*)g,
      (__attribute__((address_space(3))) unsigned int*)l, 16, 0, 0);
}

// ---------- weight transpose + f32->bf16 ----------
__global__ void __launch_bounds__(256) wconv(
    const float* __restrict__ relw, const float* __restrict__ w1,
    const float* __restrict__ w2, short* __restrict__ relwT,
    short* __restrict__ w1T, short* __restrict__ w2T) {
  int tid = blockIdx.x * 256 + threadIdx.x;
  if (tid < Dn*Dn) { int c = tid >> 8, k = tid & 255; relwT[tid] = f2b(relw[k*Dn + c]); }
  int t1 = tid - Dn*Dn;
  if (t1 >= 0 && t1 < Dn*Hn) { int c = t1 >> 8, k = t1 & 255; w1T[t1] = f2b(w1[k*Hn + c]); }
  int t2 = tid - Dn*Dn - Dn*Hn;
  if (t2 >= 0 && t2 < Hn*Dn) { int c = t2 >> 10, k = t2 & 1023; w2T[t2] = f2b(w2[k*Dn + c]); }
}

// ---------- CSR build ----------
__global__ void __launch_bounds__(256) histk(const int* __restrict__ ei, int* __restrict__ cnt) {
  int tid = blockIdx.x * 256 + threadIdx.x;
  if (tid >= Bn*En) return;
  int b = tid / En;
  int tgt = ei[tid*2 + 1];
  atomicAdd(&cnt[b*Nn + tgt], 1);
}

__global__ void __launch_bounds__(1024) scank(const int* __restrict__ cnt, int* __restrict__ offs) {
  __shared__ int wsum[16];
  __shared__ int carry;
  int tid = threadIdx.x;
  int lane = tid & 63, wid = tid >> 6;
  if (tid == 0) carry = 0;
  __syncthreads();
  for (int base = 0; base < RTOT; base += 1024) {
    int i = base + tid;
    int v = (i < RTOT) ? cnt[i] : 0;
    int s = v;
#pragma unroll
    for (int d = 1; d < 64; d <<= 1) {
      int t = __shfl_up(s, d, 64);
      if (lane >= d) s += t;
    }
    if (lane == 63) wsum[wid] = s;
    __syncthreads();
    if (wid == 0) {
      int w = (lane < 16) ? wsum[lane] : 0;
#pragma unroll
      for (int d = 1; d < 16; d <<= 1) {
        int t = __shfl_up(w, d, 64);
        if (lane >= d) w += t;
      }
      if (lane < 16) wsum[lane] = w;
    }
    __syncthreads();
    int wprev = (wid == 0) ? 0 : wsum[wid - 1];
    int total = wsum[15];
    int excl = (s - v) + wprev + carry;
    if (i < RTOT) offs[i] = excl;
    __syncthreads();
    if (tid == 0) carry += total;
    __syncthreads();
  }
  if (tid == 0) offs[RTOT] = carry;
}

__global__ void __launch_bounds__(256) fillk(const int* __restrict__ ei, const int* __restrict__ offs,
                                             int* __restrict__ cursor, int* __restrict__ eids) {
  int tid = blockIdx.x * 256 + threadIdx.x;
  if (tid >= Bn*En) return;
  int b = tid / En, e = tid - b*En;
  int tgt = ei[tid*2 + 1];
  int node = b*Nn + tgt;
  int pos = atomicAdd(&cursor[node], 1);
  eids[offs[node] + pos] = e;
}

// ---------- aggregation ----------
__global__ void __launch_bounds__(256) aggk(
    const float* __restrict__ nodef, const float* __restrict__ erel,
    const float* __restrict__ emask, const int* __restrict__ ei,
    const int* __restrict__ offs, const int* __restrict__ eids,
    float* __restrict__ sumrel, float* __restrict__ cntf, float* __restrict__ outsrc) {
  int w = (blockIdx.x * 256 + threadIdx.x) >> 6;
  int lane = threadIdx.x & 63;
  if (w >= RTOT) return;
  int b = w / Nn;
  const size_t ebase = (size_t)b * En;
  const size_t nbase = (size_t)b * Nn;
  int s0 = offs[w], s1 = offs[w + 1];
  float r0=0,r1=0,r2=0,r3=0, a0=0,a1=0,a2=0,a3=0, cf=0;
  for (int base = s0; base < s1; base += 64) {
    int k = s1 - base; if (k > 64) k = 64;
    int e = 0, sr = 0; float m = 0.f;
    if (lane < k) {
      e  = eids[base + lane];
      sr = ei[(ebase + e)*2];
      m  = emask[ebase + e];
    }
    int e0 = __shfl(e, 0), sr0 = __shfl(sr, 0);
    float m0 = __shfl(m, 0);
    float4 rvA = *(const float4*)(erel  + (ebase + e0)*Dn + lane*4);
    float4 nvA = *(const float4*)(nodef + (nbase + sr0)*Dn + lane*4);
    for (int j = 0; j < k; j++) {
      float4 rvB = make_float4(0,0,0,0), nvB = make_float4(0,0,0,0);
      float m1 = 0.f;
      if (j + 1 < k) {
        int e1 = __shfl(e, j+1), sr1 = __shfl(sr, j+1);
        m1 = __shfl(m, j+1);
        rvB = *(const float4*)(erel  + (ebase + e1)*Dn + lane*4);
        nvB = *(const float4*)(nodef + (nbase + sr1)*Dn + lane*4);
      }
      r0 += rvA.x*m0; r1 += rvA.y*m0; r2 += rvA.z*m0; r3 += rvA.w*m0;
      a0 += nvA.x*m0; a1 += nvA.y*m0; a2 += nvA.z*m0; a3 += nvA.w*m0;
      cf += m0;
      rvA = rvB; nvA = nvB; m0 = m1;
    }
  }
  size_t ob = (size_t)w*Dn + lane*4;
  *(float4*)(sumrel + ob) = make_float4(r0,r1,r2,r3);
  *(float4*)(outsrc + ob) = make_float4(a0,a1,a2,a3);
  if (lane == 0) cntf[w] = cf;
}

// ---------- helpers for 4-wave relln ----------
template<int MR>
__device__ __forceinline__ void stageX(const float* __restrict__ src, char* lds, int row0, int tid) {
#pragma unroll
  for (int i = 0; i < MR*4; i++) {
    int flat = tid + 256*i;
    int r = flat >> 6, c4 = flat & 63;
    float4 v = *(const float4*)(src + (size_t)(row0 + r)*Dn + c4*4);
    short4 s; s.x=f2b(v.x); s.y=f2b(v.y); s.z=f2b(v.z); s.w=f2b(v.w);
    int byte = r*512 + ((c4*8) ^ ((r & 7) << 4));
    *(short4*)(lds + byte) = s;
  }
}

__device__ __forceinline__ bf16x8 ldsA(const char* lds, int r, int kb) {
  int byte = r*512 + (((kb)*2) ^ ((r & 7) << 4));
  return *(const bf16x8*)(lds + byte);
}

template<int MR>
__device__ __forceinline__ void ln_write(f32x4 (&acc)[MR][4], float* red,
    const float* __restrict__ sc, const float* __restrict__ bi,
    float* __restrict__ out, int row0, int lane, int wv) {
  constexpr int R = MR*16;
  int l15 = lane & 15, l4 = lane >> 4;
  int cols[4]; float sc_c[4], bi_c[4];
#pragma unroll
  for (int n = 0; n < 4; n++) {
    cols[n] = wv*64 + n*16 + l15;
    sc_c[n] = sc[cols[n]]; bi_c[n] = bi[cols[n]];
  }
  float s1[MR][4], s2[MR][4];
#pragma unroll
  for (int m = 0; m < MR; m++)
#pragma unroll
    for (int g = 0; g < 4; g++) {
      float a = 0.f, b = 0.f;
#pragma unroll
      for (int n = 0; n < 4; n++) { float p = acc[m][n][g]; a += p; b += p*p; }
#pragma unroll
      for (int d = 1; d < 16; d <<= 1) { a += __shfl_xor(a, d, 16); b += __shfl_xor(b, d, 16); }
      s1[m][g] = a; s2[m][g] = b;
    }
  if (l15 == 0) {
#pragma unroll
    for (int m = 0; m < MR; m++)
#pragma unroll
      for (int g = 0; g < 4; g++) {
        int r = m*16 + l4*4 + g;
        red[(wv*R + r)*2]     = s1[m][g];
        red[(wv*R + r)*2 + 1] = s2[m][g];
      }
  }
  __syncthreads();
#pragma unroll
  for (int m = 0; m < MR; m++)
#pragma unroll
    for (int g = 0; g < 4; g++) {
      int r = m*16 + l4*4 + g; int rg = row0 + r;
      float t1 = 0.f, t2 = 0.f;
#pragma unroll
      for (int u = 0; u < 4; u++) { t1 += red[(u*R + r)*2]; t2 += red[(u*R + r)*2 + 1]; }
      float mean = t1 * (1.0f/Dn);
      float var  = t2 * (1.0f/Dn) - mean*mean;
      float rstd = rsqrtf(var + 1e-5f);
#pragma unroll
      for (int n = 0; n < 4; n++)
        out[(size_t)rg*Dn + cols[n]] = (acc[m][n][g] - mean)*rstd*sc_c[n] + bi_c[n];
    }
}

// ---------- K3: relln (unchanged) ----------
__global__ void __launch_bounds__(256, 4) relln(
    const float* __restrict__ sumrel, const short* __restrict__ relwT,
    const float* __restrict__ relb, const float* __restrict__ nodef,
    const float* __restrict__ cntf, const float* __restrict__ ns,
    const float* __restrict__ nb, float* __restrict__ xout) {
  constexpr int MR = 2;
  __shared__ __align__(16) char lds[16384 + 1024];
  float* red = (float*)(lds + 16384);
  int tid = threadIdx.x;
  int lane = tid & 63, wv = tid >> 6;
  int l15 = lane & 15, l4 = lane >> 4;
  int row0 = blockIdx.x * (MR*16);
  stageX<MR>(sumrel, lds, row0, tid);
  __syncthreads();
  f32x4 acc[MR][4] = {};
#pragma unroll
  for (int ks = 0; ks < 8; ks++) {
    bf16x8 af[MR], bfr[4];
#pragma unroll
    for (int m = 0; m < MR; m++) af[m] = ldsA(lds, m*16 + l15, ks*32 + l4*8);
#pragma unroll
    for (int n = 0; n < 4; n++) {
      int col = wv*64 + n*16 + l15;
      bfr[n] = *(const bf16x8*)(relwT + col*Dn + ks*32 + l4*8);
    }
#pragma unroll
    for (int m = 0; m < MR; m++)
#pragma unroll
      for (int n = 0; n < 4; n++)
        acc[m][n] = __builtin_amdgcn_mfma_f32_16x16x32_bf16(af[m], bfr[n], acc[m][n], 0, 0, 0);
  }
  int cols[4]; float rb_c[4];
#pragma unroll
  for (int n = 0; n < 4; n++) { cols[n] = wv*64 + n*16 + l15; rb_c[n] = relb[cols[n]]; }
#pragma unroll
  for (int m = 0; m < MR; m++)
#pragma unroll
    for (int g = 0; g < 4; g++) {
      int r = m*16 + l4*4 + g; int rg = row0 + r;
      float cf  = cntf[rg];
      float inv = 1.0f / fmaxf(cf, 1.0f);
#pragma unroll
      for (int n = 0; n < 4; n++) {
        float ssrc = xout[(size_t)rg*Dn + cols[n]];
        float nfv  = nodef[(size_t)rg*Dn + cols[n]];
        float aggv = (ssrc + acc[m][n][g] + cf*rb_c[n]) * inv;
        acc[m][n][g] = nfv + aggv;
      }
    }
  ln_write<MR>(acc, red, ns, nb, xout, row0, lane, wv);
}

// ---------- K4: fused FFN v3 — BM=128, 8 waves, LDS-staged weights ----------
#define FBM 128
#define O_XS 0
#define O_W1 65536
#define O_W2 98304
#define O_HS 131072
#define O_RED 147456

__global__ void __launch_bounds__(512, 2) ffnk(
    const short* __restrict__ w1T, const float* __restrict__ b1,
    const short* __restrict__ w2T, const float* __restrict__ b2,
    const float* __restrict__ fs, const float* __restrict__ fb,
    float* __restrict__ xio) {
  __shared__ __align__(16) char lds[151552];
  char* Xs = lds + O_XS;
  char* W1c = lds + O_W1;
  char* W2c = lds + O_W2;
  char* Hs = lds + O_HS;
  float* red = (float*)(lds + O_RED);

  int tid = threadIdx.x;
  int lane = tid & 63, wv = tid >> 6;
  int l15 = lane & 15, l4 = lane >> 4;
  int wm = wv >> 2, wn = wv & 3;          // 2 x 4 wave grid
  int row0 = blockIdx.x * FBM;

  // ---- stage X tile (f32 -> bf16, swizzled) ----
#pragma unroll
  for (int i = 0; i < 16; i++) {
    int f = tid + 512*i;                   // [0, 8192)
    int r = f >> 6, c4 = f & 63;
    int rg = row0 + r;
    float4 v = make_float4(0,0,0,0);
    if (rg < RTOT) v = *(const float4*)(xio + (size_t)rg*Dn + c4*4);
    short4 s; s.x=f2b(v.x); s.y=f2b(v.y); s.z=f2b(v.z); s.w=f2b(v.w);
    *(short4*)(Xs + r*512 + ((c4*8) ^ ((r & 7) << 4))) = s;
  }

  const char* w1b = (const char*)w1T;
  const char* w2b = (const char*)w2T;
  f32x4 acc2[4][4] = {};

#pragma unroll 1
  for (int hc = 0; hc < 16; hc++) {
    __syncthreads();                       // prev readers done (also covers Xs stage at hc=0)
    // ---- stage weight chunk: W1c 32KB (64 cols x 256 k), W2c 32KB (256 cols x 64 k) ----
#pragma unroll
    for (int i = 0; i < 4; i++) {
      int o = (wv*4 + i)*1024 + lane*16;
      int r = o >> 9, byte = o & 511;
      const char* src = w1b + (((size_t)(hc*64 + r)) << 9) + (byte ^ ((r & 7) << 4));
      gl16(src, W1c + (wv*4 + i)*1024);
    }
#pragma unroll
    for (int i = 0; i < 4; i++) {
      int o = (wv*4 + i)*1024 + lane*16;
      int r = o >> 7, byte = o & 127;
      const char* src = w2b + (((size_t)r) << 11) + (hc << 7) + (byte ^ ((r & 7) << 4));
      gl16(src, W2c + (wv*4 + i)*1024);
    }
    __syncthreads();                       // staging complete

    // ---- GEMM1: acc1[mf] = X(128x256) @ w1chunk(256x64), wave tile 64x16 ----
    f32x4 acc1[4] = {};
    int cl = wn*16 + l15;
#pragma unroll
    for (int ks = 0; ks < 8; ks++) {
      bf16x8 bf1 = *(const bf16x8*)(W1c + cl*512 + (((ks*32 + l4*8)*2) ^ ((cl & 7) << 4)));
#pragma unroll
      for (int mf = 0; mf < 4; mf++) {
        int rr = wm*64 + mf*16 + l15;
        bf16x8 a = *(const bf16x8*)(Xs + rr*512 + (((ks*32 + l4*8)*2) ^ ((rr & 7) << 4)));
        acc1[mf] = __builtin_amdgcn_mfma_f32_16x16x32_bf16(a, bf1, acc1[mf], 0, 0, 0);
      }
    }
    // ---- bias + gelu -> Hs (bf16, swizzled) ----
    float bb = b1[hc*64 + cl];
#pragma unroll
    for (int mf = 0; mf < 4; mf++)
#pragma unroll
      for (int g = 0; g < 4; g++) {
        int R = wm*64 + mf*16 + l4*4 + g;
        float ge = gelu_f(acc1[mf][g] + bb);
        *(short*)(Hs + ((R*128 + cl*2) ^ ((R & 7) << 4))) = f2b(ge);
      }
    __syncthreads();                       // Hs ready

    // ---- GEMM2: acc2 += H(128x64) @ w2chunk(64x256), wave tile 64x64 ----
#pragma unroll
    for (int ksl = 0; ksl < 2; ksl++) {
      bf16x8 ah[4], bw[4];
#pragma unroll
      for (int mf = 0; mf < 4; mf++) {
        int rr = wm*64 + mf*16 + l15;
        ah[mf] = *(const bf16x8*)(Hs + rr*128 + (((ksl*32 + l4*8)*2) ^ ((rr & 7) << 4)));
      }
#pragma unroll
      for (int nf = 0; nf < 4; nf++) {
        int oc = wn*64 + nf*16 + l15;
        bw[nf] = *(const bf16x8*)(W2c + oc*128 + (((ksl*32 + l4*8)*2) ^ ((oc & 7) << 4)));
      }
#pragma unroll
      for (int mf = 0; mf < 4; mf++)
#pragma unroll
        for (int nf = 0; nf < 4; nf++)
          acc2[mf][nf] = __builtin_amdgcn_mfma_f32_16x16x32_bf16(ah[mf], bw[nf], acc2[mf][nf], 0, 0, 0);
    }
  }

  // ---- epilogue: + b2 + residual, LayerNorm over 256 cols (4 wn waves share rows) ----
  float b2c[4], fsc[4], fbc[4];
#pragma unroll
  for (int nf = 0; nf < 4; nf++) {
    int col = wn*64 + nf*16 + l15;
    b2c[nf] = b2[col]; fsc[nf] = fs[col]; fbc[nf] = fb[col];
  }
#pragma unroll
  for (int mf = 0; mf < 4; mf++)
#pragma unroll
    for (int g = 0; g < 4; g++) {
      int R = wm*64 + mf*16 + l4*4 + g;
      int rg = row0 + R;
      bool ok = rg < RTOT;
      float a = 0.f, q = 0.f;
#pragma unroll
      for (int nf = 0; nf < 4; nf++) {
        int col = wn*64 + nf*16 + l15;
        float xv = ok ? xio[(size_t)rg*Dn + col] : 0.f;
        float vv = xv + acc2[mf][nf][g] + b2c[nf];
        acc2[mf][nf][g] = vv;
        a += vv; q += vv*vv;
      }
#pragma unroll
      for (int d = 1; d < 16; d <<= 1) { a += __shfl_xor(a, d, 16); q += __shfl_xor(q, d, 16); }
      if (l15 == 0) {
        red[(wn*FBM + R)*2]     = a;
        red[(wn*FBM + R)*2 + 1] = q;
      }
    }
  __syncthreads();
#pragma unroll
  for (int mf = 0; mf < 4; mf++)
#pragma unroll
    for (int g = 0; g < 4; g++) {
      int R = wm*64 + mf*16 + l4*4 + g;
      int rg = row0 + R;
      if (rg >= RTOT) continue;
      float t1 = 0.f, t2 = 0.f;
#pragma unroll
      for (int u = 0; u < 4; u++) { t1 += red[(u*FBM + R)*2]; t2 += red[(u*FBM + R)*2 + 1]; }
      float mean = t1 * (1.0f/Dn);
      float var  = t2 * (1.0f/Dn) - mean*mean;
      float rstd = rsqrtf(var + 1e-5f);
#pragma unroll
      for (int nf = 0; nf < 4; nf++) {
        int col = wn*64 + nf*16 + l15;
        xio[(size_t)rg*Dn + col] = (acc2[mf][nf][g] - mean)*rstd*fsc[nf] + fbc[nf];
      }
    }
}

// ---------- host ----------
extern "C" void kernel_launch(void* const* d_in, const int* in_sizes, int n_in,
                              void* d_out, int out_size, void* d_ws, size_t ws_size,
                              hipStream_t stream) {
  const float* nodef = (const float*)d_in[0];
  const float* erel  = (const float*)d_in[1];
  const float* emask = (const float*)d_in[2];
  const float* relw  = (const float*)d_in[3];
  const float* relb  = (const float*)d_in[4];
  const float* ns    = (const float*)d_in[5];
  const float* nb    = (const float*)d_in[6];
  const float* w1    = (const float*)d_in[7];
  const float* b1    = (const float*)d_in[8];
  const float* w2    = (const float*)d_in[9];
  const float* b2    = (const float*)d_in[10];
  const float* fs    = (const float*)d_in[11];
  const float* fb    = (const float*)d_in[12];
  const int*   ei    = (const int*)d_in[13];
  float* out = (float*)d_out;
  char* ws = (char*)d_ws;

  constexpr size_t SZ_SUMREL = (size_t)RTOT * Dn * 4;
  constexpr size_t O_CNT  = SZ_SUMREL;
  constexpr size_t O_CUR  = O_CNT + (size_t)RTOT*4;
  constexpr size_t O_OFF  = O_CUR + (size_t)RTOT*4;
  constexpr size_t O_EID  = O_OFF + ((size_t)(RTOT+1)*4 + 124);
  constexpr size_t O_CNTF = O_EID + (size_t)Bn*En*4;
  constexpr size_t O_RWT  = O_CNTF + (size_t)RTOT*4;
  constexpr size_t O_W1T  = O_RWT + (size_t)Dn*Dn*2;
  constexpr size_t O_W2T  = O_W1T + (size_t)Dn*Hn*2;
  constexpr size_t WS_NEED = O_W2T + (size_t)Hn*Dn*2;
  if (ws_size < WS_NEED) return;

  float* sumrel = (float*)(ws);
  int*   cnt    = (int*)(ws + O_CNT);
  int*   cursor = (int*)(ws + O_CUR);
  int*   offs   = (int*)(ws + O_OFF);
  int*   eids   = (int*)(ws + O_EID);
  float* cntf   = (float*)(ws + O_CNTF);
  short* relwT  = (short*)(ws + O_RWT);
  short* w1T    = (short*)(ws + O_W1T);
  short* w2T    = (short*)(ws + O_W2T);

  hipMemsetAsync(ws + O_CNT, 0, (size_t)RTOT*8, stream);

  wconv<<<(Dn*Dn + Dn*Hn + Hn*Dn) / 256, 256, 0, stream>>>(relw, w1, w2, relwT, w1T, w2T);
  histk<<<(Bn*En) / 256, 256, 0, stream>>>(ei, cnt);
  scank<<<1, 1024, 0, stream>>>(cnt, offs);
  fillk<<<(Bn*En) / 256, 256, 0, stream>>>(ei, offs, cursor, eids);
  aggk<<<(RTOT + 3) / 4, 256, 0, stream>>>(nodef, erel, emask, ei, offs, eids, sumrel, cntf, out);
  relln<<<RTOT / 32, 256, 0, stream>>>(sumrel, relwT, relb, nodef, cntf, ns, nb, out);
  ffnk<<<(RTOT + FBM - 1) / FBM, 512, 0, stream>>>(w1T, b1, w2T, b2, fs, fb, out);
}